// Round 1
// baseline (228.647 us; speedup 1.0000x reference)
//
#include <hip/hip_runtime.h>
#include <stdint.h>

#define T_ 2048
#define BB_ 4

typedef __bf16 bf16x8 __attribute__((ext_vector_type(8)));
typedef float f32x4 __attribute__((ext_vector_type(4)));
typedef unsigned short u16x8 __attribute__((ext_vector_type(8)));

__device__ __forceinline__ unsigned short f2b(float f) {
    unsigned int u = __builtin_bit_cast(unsigned int, f);
    return (unsigned short)((u + 0x7fffu + ((u >> 16) & 1u)) >> 16);
}

__device__ __forceinline__ void gload16(const void* g, const void* lds) {
    __builtin_amdgcn_global_load_lds(
        (__attribute__((address_space(1))) void*)(uintptr_t)g,
        (__attribute__((address_space(3))) void*)(uintptr_t)(unsigned int)(uintptr_t)lds,
        16, 0, 0);
}

__device__ __forceinline__ bf16x8 ld_b8(const unsigned short* p) {
    return *(const bf16x8*)p;
}

#define MFMA16(a, b, c) __builtin_amdgcn_mfma_f32_16x16x32_bf16((a), (b), (c), 0, 0, 0)

// ---------------- fp32 -> bf16 elementwise ----------------
__global__ __launch_bounds__(256) void k_cvt(const float* __restrict__ in,
                                             unsigned short* __restrict__ out, int n) {
    int i = (blockIdx.x * 256 + threadIdx.x) * 4;
    const int stride = gridDim.x * 256 * 4;
    for (; i < n; i += stride) {
        const float4 v = *(const float4*)(in + i);
        ushort4 o = make_ushort4(f2b(v.x), f2b(v.y), f2b(v.z), f2b(v.w));
        *(ushort4*)(out + i) = o;
    }
}

// ---------------- fp32 (K x N) -> bf16 transposed (N x K) ----------------
template <int K, int N>
__global__ __launch_bounds__(256) void k_cvt_T(const float* __restrict__ W,
                                               unsigned short* __restrict__ WT) {
    __shared__ unsigned short t_[64][72];
    const int nt = blockIdx.x % (N / 64), kt = blockIdx.x / (N / 64);
    const int tid = threadIdx.x;
    const int r = tid >> 2, c = (tid & 3) * 16;
    const float* src = W + (size_t)(kt * 64 + r) * N + nt * 64 + c;
#pragma unroll
    for (int j = 0; j < 16; j += 4) {
        float4 v = *(const float4*)(src + j);
        t_[r][c + j + 0] = f2b(v.x);
        t_[r][c + j + 1] = f2b(v.y);
        t_[r][c + j + 2] = f2b(v.z);
        t_[r][c + j + 3] = f2b(v.w);
    }
    __syncthreads();
    unsigned short* dst = WT + (size_t)(nt * 64 + r) * K + kt * 64 + c;
#pragma unroll
    for (int j = 0; j < 16; ++j) dst[j] = t_[c + j][r];
}

// ---------------- bf16 GEMM: C[M][N] = A[M][K] * Bt[N][K]^T ----------------
// 128x128 tile, 4 waves (each 64x64), BK=32, global_load_lds staging.
template <int K, int OUTF>
__global__ __launch_bounds__(256) void k_gemm(const unsigned short* __restrict__ A,
                                              const unsigned short* __restrict__ Bt,
                                              void* __restrict__ Cv, int N) {
    __shared__ unsigned short As[128 * 32];
    __shared__ unsigned short Bs[128 * 32];
    const int tid = threadIdx.x;
    const int lane = tid & 63;
    const int wid = tid >> 6;
    const int wr = wid >> 1, wc = wid & 1;
    const int m0 = blockIdx.y * 128, n0 = blockIdx.x * 128;
    const int arow = lane >> 2;         // row within 16-row chunk
    const int acol = (lane & 3) * 8;    // k-element offset
    f32x4 acc[4][4] = {};

    const unsigned short* Abase = A + (size_t)(m0 + wid * 32 + arow) * K + acol;
    const unsigned short* Bbase = Bt + (size_t)(n0 + wid * 32 + arow) * K + acol;

    for (int k0 = 0; k0 < K; k0 += 32) {
        gload16(Abase + k0, As + (wid * 2) * 512);
        gload16(Abase + k0 + 16 * K, As + (wid * 2 + 1) * 512);
        gload16(Bbase + k0, Bs + (wid * 2) * 512);
        gload16(Bbase + k0 + 16 * K, Bs + (wid * 2 + 1) * 512);
        __syncthreads();
        bf16x8 af[4], bfr[4];
#pragma unroll
        for (int i = 0; i < 4; ++i) {
            af[i] = ld_b8(As + (wr * 64 + i * 16 + (lane & 15)) * 32 + (lane >> 4) * 8);
            bfr[i] = ld_b8(Bs + (wc * 64 + i * 16 + (lane & 15)) * 32 + (lane >> 4) * 8);
        }
#pragma unroll
        for (int i = 0; i < 4; ++i)
#pragma unroll
            for (int j = 0; j < 4; ++j) acc[i][j] = MFMA16(af[i], bfr[j], acc[i][j]);
        __syncthreads();
    }
    const int crow = m0 + wr * 64 + (lane >> 4) * 4;
    const int ccol = n0 + wc * 64 + (lane & 15);
#pragma unroll
    for (int i = 0; i < 4; ++i)
#pragma unroll
        for (int j = 0; j < 4; ++j)
#pragma unroll
            for (int r = 0; r < 4; ++r) {
                const size_t idx = (size_t)(crow + i * 16 + r) * N + ccol + j * 16;
                if (OUTF)
                    ((float*)Cv)[idx] = acc[i][j][r];
                else
                    ((unsigned short*)Cv)[idx] = f2b(acc[i][j][r]);
            }
}

// ---------------- extract V^T: vt[bh][dh][t] from qkv ----------------
__global__ __launch_bounds__(256) void k_vt(const unsigned short* __restrict__ qkv,
                                            unsigned short* __restrict__ vt) {
    __shared__ unsigned short t_[64][72];
    const int bh = blockIdx.x & 63, tt = blockIdx.x >> 6;
    const int b = bh >> 4, h = bh & 15;
    const int tid = threadIdx.x;
    const int r = tid >> 2, c = (tid & 3) * 16;
    const unsigned short* src =
        qkv + (size_t)(b * T_ + tt * 64 + r) * 3072 + 2048 + h * 64 + c;
    *(u16x8*)&t_[r][c] = *(const u16x8*)src;
    *(u16x8*)&t_[r][c + 8] = *(const u16x8*)(src + 8);
    __syncthreads();
    unsigned short* dst = vt + (size_t)(bh * 64 + r) * T_ + tt * 64 + c;
#pragma unroll
    for (int j = 0; j < 16; ++j) dst[j] = t_[c + j][r];
}

// ---------------- causal flash attention ----------------
// block = 4 waves; 64 q-rows per block (16 per wave); K/V tiles of 64 keys in
// LDS (XOR-swizzled via pre-swizzled global source); online softmax; P via
// padded wave-private LDS.
__global__ __launch_bounds__(256) void k_attn(const unsigned short* __restrict__ qkv,
                                              const unsigned short* __restrict__ vt,
                                              unsigned short* __restrict__ ao) {
    __shared__ unsigned short Ks[64 * 64];
    __shared__ unsigned short Vs[64 * 64];
    __shared__ unsigned short Ps[4][16 * 72];
    const int bh = blockIdx.x & 63;
    const int qt = 31 - (blockIdx.x >> 6);  // heavy tiles dispatched first
    const int b = bh >> 4, h = bh & 15;
    const int tid = threadIdx.x, lane = tid & 63, w = tid >> 6;
    const int l4 = lane >> 4, l15 = lane & 15;

    // Q fragments (held in registers for the whole block)
    const int qrow = qt * 64 + w * 16 + l15;
    const unsigned short* qb = qkv + (size_t)(b * T_ + qrow) * 3072 + h * 64;
    const bf16x8 qf0 = ld_b8(qb + l4 * 8);
    const bf16x8 qf1 = ld_b8(qb + 32 + l4 * 8);

    float m_r[4] = {-1e30f, -1e30f, -1e30f, -1e30f};
    float l_r[4] = {0.f, 0.f, 0.f, 0.f};
    f32x4 o[4] = {};

    // staging geometry: chunk c = w*2+j covers rows c*8 + lane/8, 16B per lane.
    // XOR swizzle: LDS[row][cb] holds global[row][cb ^ ((row&7)<<4)].
    const int sr0 = w * 16 + (lane >> 3);
    const int scol = 8 * ((lane & 7) ^ (lane >> 3));  // pre-swizzled source col (elems)
    const unsigned short* Kg = qkv + (size_t)(b * T_) * 3072 + 1024 + h * 64;
    const unsigned short* Vg = vt + (size_t)(bh * 64) * T_;

    for (int kt = 0; kt <= qt; ++kt) {
        gload16(Kg + (size_t)(kt * 64 + sr0) * 3072 + scol, Ks + (w * 2) * 512);
        gload16(Kg + (size_t)(kt * 64 + sr0 + 8) * 3072 + scol, Ks + (w * 2 + 1) * 512);
        gload16(Vg + (size_t)sr0 * T_ + kt * 64 + scol, Vs + (w * 2) * 512);
        gload16(Vg + (size_t)(sr0 + 8) * T_ + kt * 64 + scol, Vs + (w * 2 + 1) * 512);
        __syncthreads();

        // S = Q K^T   (rows q = l4*4+r, cols key = i*16+l15)
        float tv[4][4];
#pragma unroll
        for (int i = 0; i < 4; ++i) {
            const int key = i * 16 + l15;
            const int sw = (key & 7) << 4;
            const bf16x8 kf0 = ld_b8(Ks + (key * 128 + ((l4 * 16) ^ sw)) / 2);
            const bf16x8 kf1 = ld_b8(Ks + (key * 128 + ((l4 * 16 + 64) ^ sw)) / 2);
            f32x4 sacc = {};
            sacc = MFMA16(qf0, kf0, sacc);
            sacc = MFMA16(qf1, kf1, sacc);
#pragma unroll
            for (int r = 0; r < 4; ++r) {
                float t = sacc[r] * 0.18033688f;  // (1/sqrt(64)) * log2(e)
                if (kt == qt && (i * 16 + l15) > (w * 16 + l4 * 4 + r)) t = -1e30f;
                tv[i][r] = t;
            }
        }
        // online softmax update
        float fac[4];
#pragma unroll
        for (int r = 0; r < 4; ++r) {
            float mx = fmaxf(fmaxf(tv[0][r], tv[1][r]), fmaxf(tv[2][r], tv[3][r]));
            mx = fmaxf(mx, __shfl_xor(mx, 1));
            mx = fmaxf(mx, __shfl_xor(mx, 2));
            mx = fmaxf(mx, __shfl_xor(mx, 4));
            mx = fmaxf(mx, __shfl_xor(mx, 8));
            const float mnew = fmaxf(m_r[r], mx);
            fac[r] = __builtin_amdgcn_exp2f(m_r[r] - mnew);
            m_r[r] = mnew;
        }
        float rs[4] = {0.f, 0.f, 0.f, 0.f};
#pragma unroll
        for (int i = 0; i < 4; ++i)
#pragma unroll
            for (int r = 0; r < 4; ++r) {
                const float p = __builtin_amdgcn_exp2f(tv[i][r] - m_r[r]);
                rs[r] += p;
                Ps[w][(l4 * 4 + r) * 72 + i * 16 + l15] = f2b(p);
            }
#pragma unroll
        for (int r = 0; r < 4; ++r) {
            float s = rs[r];
            s += __shfl_xor(s, 1);
            s += __shfl_xor(s, 2);
            s += __shfl_xor(s, 4);
            s += __shfl_xor(s, 8);
            l_r[r] = l_r[r] * fac[r] + s;
#pragma unroll
            for (int ni = 0; ni < 4; ++ni) o[ni][r] *= fac[r];
        }
        // O += P V   (A = P rows q=l15, k = keys; B = V^T rows dh)
#pragma unroll
        for (int st = 0; st < 2; ++st) {
            const bf16x8 pf = ld_b8(&Ps[w][l15 * 72 + st * 32 + l4 * 8]);
#pragma unroll
            for (int ni = 0; ni < 4; ++ni) {
                const int dh = ni * 16 + l15;
                const int sw = (dh & 7) << 4;
                const bf16x8 vf = ld_b8(Vs + (dh * 128 + ((st * 64 + l4 * 16) ^ sw)) / 2);
                o[ni] = MFMA16(pf, vf, o[ni]);
            }
        }
        __syncthreads();
    }
    // epilogue: normalize + store bf16 to [b, t, h, dh]
    unsigned short* aop = ao + (size_t)(b * T_ + qt * 64 + w * 16) * 1024 + h * 64;
#pragma unroll
    for (int r = 0; r < 4; ++r) {
        const float inv = 1.0f / l_r[r];
#pragma unroll
        for (int ni = 0; ni < 4; ++ni)
            aop[(size_t)(l4 * 4 + r) * 1024 + ni * 16 + l15] = f2b(o[ni][r] * inv);
    }
}

extern "C" void kernel_launch(void* const* d_in, const int* in_sizes, int n_in,
                              void* d_out, int out_size, void* d_ws, size_t ws_size,
                              hipStream_t stream) {
    (void)in_sizes; (void)n_in; (void)out_size; (void)ws_size;
    const float* x = (const float*)d_in[0];
    const float* Wqkv = (const float*)d_in[1];
    const float* Wout = (const float*)d_in[2];
    char* ws = (char*)d_ws;
    unsigned short* xb = (unsigned short*)(ws + 0);          // 16 MB
    unsigned short* wqkvT = (unsigned short*)(ws + 16777216);   // 6 MB  (3072 x 1024)
    unsigned short* woutT = (unsigned short*)(ws + 23068672);   // 2 MB  (1024 x 1024)
    unsigned short* qkvb = (unsigned short*)(ws + 25165824);    // 48 MB (8192 x 3072)
    unsigned short* vt = (unsigned short*)(ws + 75497472);      // 16 MB (64 heads x 64 x 2048)
    unsigned short* ao = (unsigned short*)(ws + 92274688);      // 16 MB (8192 x 1024)

    k_cvt<<<2048, 256, 0, stream>>>(x, xb, 4 * T_ * 1024);
    k_cvt_T<1024, 3072><<<16 * 48, 256, 0, stream>>>(Wqkv, wqkvT);
    k_cvt_T<1024, 1024><<<16 * 16, 256, 0, stream>>>(Wout, woutT);
    k_gemm<1024, 0><<<dim3(24, 64), 256, 0, stream>>>(xb, wqkvT, (void*)qkvb, 3072);
    k_vt<<<2048, 256, 0, stream>>>(qkvb, vt);
    k_attn<<<2048, 256, 0, stream>>>(qkvb, vt, ao);
    k_gemm<1024, 1><<<dim3(8, 64), 256, 0, stream>>>(ao, woutT, d_out, 1024);
}

// Round 2
// 190.741 us; speedup vs baseline: 1.1987x; 1.1987x over previous
//
#include <hip/hip_runtime.h>
#include <stdint.h>

#define T_ 2048
#define BB_ 4

typedef __bf16 bf16x8 __attribute__((ext_vector_type(8)));
typedef float f32x4 __attribute__((ext_vector_type(4)));
typedef unsigned short u16x8 __attribute__((ext_vector_type(8)));

__device__ __forceinline__ unsigned short f2b(float f) {
    unsigned int u = __builtin_bit_cast(unsigned int, f);
    return (unsigned short)((u + 0x7fffu + ((u >> 16) & 1u)) >> 16);
}

__device__ __forceinline__ unsigned cvt_pk(float lo, float hi) {
    unsigned r;
    asm("v_cvt_pk_bf16_f32 %0, %1, %2" : "=v"(r) : "v"(lo), "v"(hi));
    return r;
}

__device__ __forceinline__ void gload16(const void* g, const void* lds) {
    __builtin_amdgcn_global_load_lds(
        (__attribute__((address_space(1))) void*)(uintptr_t)g,
        (__attribute__((address_space(3))) void*)(uintptr_t)(unsigned int)(uintptr_t)lds,
        16, 0, 0);
}

__device__ __forceinline__ bf16x8 ld_b8(const unsigned short* p) {
    return *(const bf16x8*)p;
}

#define MFMA16(a, b, c) __builtin_amdgcn_mfma_f32_16x16x32_bf16((a), (b), (c), 0, 0, 0)

// ---------------- fp32 -> bf16 elementwise ----------------
__global__ __launch_bounds__(256) void k_cvt(const float* __restrict__ in,
                                             unsigned short* __restrict__ out, int n) {
    int i = (blockIdx.x * 256 + threadIdx.x) * 4;
    const int stride = gridDim.x * 256 * 4;
    for (; i < n; i += stride) {
        const float4 v = *(const float4*)(in + i);
        ushort4 o = make_ushort4(f2b(v.x), f2b(v.y), f2b(v.z), f2b(v.w));
        *(ushort4*)(out + i) = o;
    }
}

// ---------------- fp32 (K x N) -> bf16 transposed (N x K) ----------------
template <int K, int N>
__global__ __launch_bounds__(256) void k_cvt_T(const float* __restrict__ W,
                                               unsigned short* __restrict__ WT) {
    __shared__ unsigned short t_[64][72];
    const int nt = blockIdx.x % (N / 64), kt = blockIdx.x / (N / 64);
    const int tid = threadIdx.x;
    const int r = tid >> 2, c = (tid & 3) * 16;
    const float* src = W + (size_t)(kt * 64 + r) * N + nt * 64 + c;
#pragma unroll
    for (int j = 0; j < 16; j += 4) {
        float4 v = *(const float4*)(src + j);
        t_[r][c + j + 0] = f2b(v.x);
        t_[r][c + j + 1] = f2b(v.y);
        t_[r][c + j + 2] = f2b(v.z);
        t_[r][c + j + 3] = f2b(v.w);
    }
    __syncthreads();
    unsigned short* dst = WT + (size_t)(nt * 64 + r) * K + kt * 64 + c;
#pragma unroll
    for (int j = 0; j < 16; ++j) dst[j] = t_[c + j][r];
}

// ---------------- bf16 GEMM: C[M][N] = A[M][K] * Bt[N][K]^T ----------------
template <int K, int OUTF>
__global__ __launch_bounds__(256) void k_gemm(const unsigned short* __restrict__ A,
                                              const unsigned short* __restrict__ Bt,
                                              void* __restrict__ Cv, int N) {
    __shared__ unsigned short As[128 * 32];
    __shared__ unsigned short Bs[128 * 32];
    const int tid = threadIdx.x;
    const int lane = tid & 63;
    const int wid = tid >> 6;
    const int wr = wid >> 1, wc = wid & 1;
    const int m0 = blockIdx.y * 128, n0 = blockIdx.x * 128;
    const int arow = lane >> 2;
    const int acol = (lane & 3) * 8;
    f32x4 acc[4][4] = {};

    const unsigned short* Abase = A + (size_t)(m0 + wid * 32 + arow) * K + acol;
    const unsigned short* Bbase = Bt + (size_t)(n0 + wid * 32 + arow) * K + acol;

    for (int k0 = 0; k0 < K; k0 += 32) {
        gload16(Abase + k0, As + (wid * 2) * 512);
        gload16(Abase + k0 + 16 * K, As + (wid * 2 + 1) * 512);
        gload16(Bbase + k0, Bs + (wid * 2) * 512);
        gload16(Bbase + k0 + 16 * K, Bs + (wid * 2 + 1) * 512);
        __syncthreads();
        bf16x8 af[4], bfr[4];
#pragma unroll
        for (int i = 0; i < 4; ++i) {
            af[i] = ld_b8(As + (wr * 64 + i * 16 + (lane & 15)) * 32 + (lane >> 4) * 8);
            bfr[i] = ld_b8(Bs + (wc * 64 + i * 16 + (lane & 15)) * 32 + (lane >> 4) * 8);
        }
#pragma unroll
        for (int i = 0; i < 4; ++i)
#pragma unroll
            for (int j = 0; j < 4; ++j) acc[i][j] = MFMA16(af[i], bfr[j], acc[i][j]);
        __syncthreads();
    }
    const int crow = m0 + wr * 64 + (lane >> 4) * 4;
    const int ccol = n0 + wc * 64 + (lane & 15);
#pragma unroll
    for (int i = 0; i < 4; ++i)
#pragma unroll
        for (int j = 0; j < 4; ++j)
#pragma unroll
            for (int r = 0; r < 4; ++r) {
                const size_t idx = (size_t)(crow + i * 16 + r) * N + ccol + j * 16;
                if (OUTF)
                    ((float*)Cv)[idx] = acc[i][j][r];
                else
                    ((unsigned short*)Cv)[idx] = f2b(acc[i][j][r]);
            }
}

// ---------------- extract V^T: vt[bh][dh][t] from qkv ----------------
__global__ __launch_bounds__(256) void k_vt(const unsigned short* __restrict__ qkv,
                                            unsigned short* __restrict__ vt) {
    __shared__ unsigned short t_[64][72];
    const int bh = blockIdx.x & 63, tt = blockIdx.x >> 6;
    const int b = bh >> 4, h = bh & 15;
    const int tid = threadIdx.x;
    const int r = tid >> 2, c = (tid & 3) * 16;
    const unsigned short* src =
        qkv + (size_t)(b * T_ + tt * 64 + r) * 3072 + 2048 + h * 64 + c;
    *(u16x8*)&t_[r][c] = *(const u16x8*)src;
    *(u16x8*)&t_[r][c + 8] = *(const u16x8*)(src + 8);
    __syncthreads();
    unsigned short* dst = vt + (size_t)(bh * 64 + r) * T_ + tt * 64 + c;
#pragma unroll
    for (int j = 0; j < 16; ++j) dst[j] = t_[c + j][r];
}

// ---------------- causal flash attention (swapped QK^T, in-lane softmax) ----
// 4 waves, 64 q-rows/block. S^T = mfma(K,Q): lane holds 16 scores for q=lane&15,
// keys i*16 + (lane>>4)*4 + r. Row softmax: 15 in-lane fmax/add + 2 shfl_xor.
// Defer-max (thr=8), peeled diagonal, K/V double-buffered (1 barrier/tile).
__global__ __launch_bounds__(256) void k_attn(const unsigned short* __restrict__ qkv,
                                              const unsigned short* __restrict__ vt,
                                              unsigned short* __restrict__ ao) {
    __shared__ unsigned short Ks[2 * 4096];
    __shared__ unsigned short Vs[2 * 4096];
    __shared__ unsigned short Ps[4][16 * 72];
    const int bh = blockIdx.x & 63;
    const int qt = 31 - (blockIdx.x >> 6);  // heavy tiles first
    const int b = bh >> 4, h = bh & 15;
    const int tid = threadIdx.x, lane = tid & 63, w = tid >> 6;
    const int l4 = lane >> 4, l15 = lane & 15;

    // Q fragment rows q = w*16 + l15, pre-scaled by (1/sqrt(64))*log2(e)
    const unsigned short* qb =
        qkv + (size_t)(b * T_ + qt * 64 + w * 16 + l15) * 3072 + h * 64;
    bf16x8 qf0, qf1;
    {
        const bf16x8 r0 = ld_b8(qb + l4 * 8);
        const bf16x8 r1 = ld_b8(qb + 32 + l4 * 8);
#pragma unroll
        for (int j = 0; j < 8; ++j) {
            qf0[j] = (__bf16)((float)r0[j] * 0.18033688f);
            qf1[j] = (__bf16)((float)r1[j] * 0.18033688f);
        }
    }

    float m_s = -1e30f, l_s = 0.f;  // stats for q = l15 (replicated over l4)
    f32x4 o[4] = {};                // o[ni][r]: row q=l4*4+r, col dh=ni*16+l15

    const int sr0 = w * 16 + (lane >> 3);
    const int scol = 8 * ((lane & 7) ^ (lane >> 3));  // inverse-swizzled source col
    const unsigned short* Kg = qkv + (size_t)(b * T_) * 3072 + 1024 + h * 64;
    const unsigned short* Vg = vt + (size_t)(bh * 64) * T_;

    auto STAGE = [&](int kt, int bi) {
        unsigned short* Kb = Ks + bi * 4096;
        unsigned short* Vb = Vs + bi * 4096;
        gload16(Kg + (size_t)(kt * 64 + sr0) * 3072 + scol, Kb + (w * 2) * 512);
        gload16(Kg + (size_t)(kt * 64 + sr0 + 8) * 3072 + scol, Kb + (w * 2 + 1) * 512);
        gload16(Vg + (size_t)sr0 * T_ + kt * 64 + scol, Vb + (w * 2) * 512);
        gload16(Vg + (size_t)(sr0 + 8) * T_ + kt * 64 + scol, Vb + (w * 2 + 1) * 512);
    };

    auto COMPUTE = [&](int bi, bool masked) {
        const unsigned short* Kb = Ks + bi * 4096;
        const unsigned short* Vb = Vs + bi * 4096;
        float tv[4][4];
        __builtin_amdgcn_s_setprio(1);
#pragma unroll
        for (int i = 0; i < 4; ++i) {
            const int key = i * 16 + l15;
            const int sw = (key & 7) << 4;
            const bf16x8 kf0 = ld_b8(Kb + (key * 128 + ((l4 * 16) ^ sw)) / 2);
            const bf16x8 kf1 = ld_b8(Kb + (key * 128 + ((l4 * 16 + 64) ^ sw)) / 2);
            f32x4 sacc = {};
            sacc = MFMA16(kf0, qf0, sacc);
            sacc = MFMA16(kf1, qf1, sacc);
#pragma unroll
            for (int r = 0; r < 4; ++r) tv[i][r] = sacc[r];
        }
        __builtin_amdgcn_s_setprio(0);
        if (masked) {
#pragma unroll
            for (int i = 0; i < 4; ++i)
#pragma unroll
                for (int r = 0; r < 4; ++r)
                    if (i * 16 + l4 * 4 + r > w * 16 + l15) tv[i][r] = -1e30f;
        }
        // row max for q=l15: 15 in-lane + 2 cross-lane
        float mi[4];
#pragma unroll
        for (int i = 0; i < 4; ++i)
            mi[i] = fmaxf(fmaxf(tv[i][0], tv[i][1]), fmaxf(tv[i][2], tv[i][3]));
        float mx = fmaxf(fmaxf(mi[0], mi[1]), fmaxf(mi[2], mi[3]));
        mx = fmaxf(mx, __shfl_xor(mx, 16));
        mx = fmaxf(mx, __shfl_xor(mx, 32));
        if (__any(mx > m_s + 8.0f)) {  // defer-max: rescale only on real growth
            const float mnew = fmaxf(m_s, mx);
            const float fac = __builtin_amdgcn_exp2f(m_s - mnew);
            m_s = mnew;
            l_s *= fac;
#pragma unroll
            for (int r = 0; r < 4; ++r) {
                const float fr = __shfl(fac, (l4 << 4) | (l4 * 4 + r));
#pragma unroll
                for (int ni = 0; ni < 4; ++ni) o[ni][r] *= fr;
            }
        }
        float rs = 0.f;
        unsigned pw[8];
#pragma unroll
        for (int i = 0; i < 4; ++i) {
            float p[4];
#pragma unroll
            for (int r = 0; r < 4; ++r) {
                p[r] = __builtin_amdgcn_exp2f(tv[i][r] - m_s);
                rs += p[r];
            }
            pw[i * 2 + 0] = cvt_pk(p[0], p[1]);
            pw[i * 2 + 1] = cvt_pk(p[2], p[3]);
        }
        rs += __shfl_xor(rs, 16);
        rs += __shfl_xor(rs, 32);
        l_s += rs;
#pragma unroll
        for (int i = 0; i < 4; ++i) {
            *(unsigned*)&Ps[w][l15 * 72 + i * 16 + l4 * 4] = pw[i * 2];
            *(unsigned*)&Ps[w][l15 * 72 + i * 16 + l4 * 4 + 2] = pw[i * 2 + 1];
        }
        __builtin_amdgcn_s_setprio(1);
#pragma unroll
        for (int st = 0; st < 2; ++st) {
            const bf16x8 pf = ld_b8(&Ps[w][l15 * 72 + st * 32 + l4 * 8]);
#pragma unroll
            for (int ni = 0; ni < 4; ++ni) {
                const int dh = ni * 16 + l15;
                const int sw = (dh & 7) << 4;
                const bf16x8 vf = ld_b8(Vb + (dh * 128 + ((st * 64 + l4 * 16) ^ sw)) / 2);
                o[ni] = MFMA16(pf, vf, o[ni]);
            }
        }
        __builtin_amdgcn_s_setprio(0);
    };

    STAGE(0, 0);
    __syncthreads();
    for (int kt = 0; kt < qt; ++kt) {
        STAGE(kt + 1, (kt + 1) & 1);
        COMPUTE(kt & 1, false);
        __syncthreads();
    }
    COMPUTE(qt & 1, true);

    // epilogue: fetch per-row l via shfl, normalize, store bf16 [b,t,h,dh]
    unsigned short* aop = ao + (size_t)(b * T_ + qt * 64 + w * 16) * 1024 + h * 64;
#pragma unroll
    for (int r = 0; r < 4; ++r) {
        const float lr = __shfl(l_s, (l4 << 4) | (l4 * 4 + r));
        const float inv = 1.0f / lr;
#pragma unroll
        for (int ni = 0; ni < 4; ++ni)
            aop[(size_t)(l4 * 4 + r) * 1024 + ni * 16 + l15] = f2b(o[ni][r] * inv);
    }
}

extern "C" void kernel_launch(void* const* d_in, const int* in_sizes, int n_in,
                              void* d_out, int out_size, void* d_ws, size_t ws_size,
                              hipStream_t stream) {
    (void)in_sizes; (void)n_in; (void)out_size; (void)ws_size;
    const float* x = (const float*)d_in[0];
    const float* Wqkv = (const float*)d_in[1];
    const float* Wout = (const float*)d_in[2];
    char* ws = (char*)d_ws;
    unsigned short* xb = (unsigned short*)(ws + 0);             // 16 MB
    unsigned short* wqkvT = (unsigned short*)(ws + 16777216);   // 6 MB  (3072 x 1024)
    unsigned short* woutT = (unsigned short*)(ws + 23068672);   // 2 MB  (1024 x 1024)
    unsigned short* qkvb = (unsigned short*)(ws + 25165824);    // 48 MB (8192 x 3072)
    unsigned short* vt = (unsigned short*)(ws + 75497472);      // 16 MB (64 heads x 64 x 2048)
    unsigned short* ao = (unsigned short*)(ws + 92274688);      // 16 MB (8192 x 1024)

    k_cvt<<<2048, 256, 0, stream>>>(x, xb, 4 * T_ * 1024);
    k_cvt_T<1024, 3072><<<16 * 48, 256, 0, stream>>>(Wqkv, wqkvT);
    k_cvt_T<1024, 1024><<<16 * 16, 256, 0, stream>>>(Wout, woutT);
    k_gemm<1024, 0><<<dim3(24, 64), 256, 0, stream>>>(xb, wqkvT, (void*)qkvb, 3072);
    k_vt<<<2048, 256, 0, stream>>>(qkvb, vt);
    k_attn<<<2048, 256, 0, stream>>>(qkvb, vt, ao);
    k_gemm<1024, 1><<<dim3(8, 64), 256, 0, stream>>>(ao, woutT, d_out, 1024);
}

// Round 3
// 187.674 us; speedup vs baseline: 1.2183x; 1.0163x over previous
//
#include <hip/hip_runtime.h>
#include <stdint.h>

#define T_ 2048
#define BB_ 4

typedef __bf16 bf16x8 __attribute__((ext_vector_type(8)));
typedef float f32x4 __attribute__((ext_vector_type(4)));
typedef unsigned short u16x8 __attribute__((ext_vector_type(8)));

__device__ __forceinline__ unsigned short f2b(float f) {
    unsigned int u = __builtin_bit_cast(unsigned int, f);
    return (unsigned short)((u + 0x7fffu + ((u >> 16) & 1u)) >> 16);
}

__device__ __forceinline__ unsigned cvt_pk(float lo, float hi) {
    unsigned r;
    asm("v_cvt_pk_bf16_f32 %0, %1, %2" : "=v"(r) : "v"(lo), "v"(hi));
    return r;
}

__device__ __forceinline__ void gload16(const void* g, const void* lds) {
    __builtin_amdgcn_global_load_lds(
        (__attribute__((address_space(1))) void*)(uintptr_t)g,
        (__attribute__((address_space(3))) void*)(uintptr_t)(unsigned int)(uintptr_t)lds,
        16, 0, 0);
}

__device__ __forceinline__ bf16x8 ld_b8(const unsigned short* p) {
    return *(const bf16x8*)p;
}

#define MFMA16(a, b, c) __builtin_amdgcn_mfma_f32_16x16x32_bf16((a), (b), (c), 0, 0, 0)

// ---------------- fp32 -> bf16 elementwise ----------------
__global__ __launch_bounds__(256) void k_cvt(const float* __restrict__ in,
                                             unsigned short* __restrict__ out, int n) {
    int i = (blockIdx.x * 256 + threadIdx.x) * 4;
    const int stride = gridDim.x * 256 * 4;
    for (; i < n; i += stride) {
        const float4 v = *(const float4*)(in + i);
        ushort4 o = make_ushort4(f2b(v.x), f2b(v.y), f2b(v.z), f2b(v.w));
        *(ushort4*)(out + i) = o;
    }
}

// ---------------- fp32 (K x N) -> bf16 transposed (N x K) ----------------
template <int K, int N>
__global__ __launch_bounds__(256) void k_cvt_T(const float* __restrict__ W,
                                               unsigned short* __restrict__ WT) {
    __shared__ unsigned short t_[64][72];
    const int nt = blockIdx.x % (N / 64), kt = blockIdx.x / (N / 64);
    const int tid = threadIdx.x;
    const int r = tid >> 2, c = (tid & 3) * 16;
    const float* src = W + (size_t)(kt * 64 + r) * N + nt * 64 + c;
#pragma unroll
    for (int j = 0; j < 16; j += 4) {
        float4 v = *(const float4*)(src + j);
        t_[r][c + j + 0] = f2b(v.x);
        t_[r][c + j + 1] = f2b(v.y);
        t_[r][c + j + 2] = f2b(v.z);
        t_[r][c + j + 3] = f2b(v.w);
    }
    __syncthreads();
    unsigned short* dst = WT + (size_t)(nt * 64 + r) * K + kt * 64 + c;
#pragma unroll
    for (int j = 0; j < 16; ++j) dst[j] = t_[c + j][r];
}

// ---------------- bf16 GEMM: C[M][N] = A[M][K] * Bt[N][K]^T ----------------
template <int K, int OUTF>
__global__ __launch_bounds__(256) void k_gemm(const unsigned short* __restrict__ A,
                                              const unsigned short* __restrict__ Bt,
                                              void* __restrict__ Cv, int N) {
    __shared__ unsigned short As[128 * 32];
    __shared__ unsigned short Bs[128 * 32];
    const int tid = threadIdx.x;
    const int lane = tid & 63;
    const int wid = tid >> 6;
    const int wr = wid >> 1, wc = wid & 1;
    const int m0 = blockIdx.y * 128, n0 = blockIdx.x * 128;
    const int arow = lane >> 2;
    const int acol = (lane & 3) * 8;
    f32x4 acc[4][4] = {};

    const unsigned short* Abase = A + (size_t)(m0 + wid * 32 + arow) * K + acol;
    const unsigned short* Bbase = Bt + (size_t)(n0 + wid * 32 + arow) * K + acol;

    for (int k0 = 0; k0 < K; k0 += 32) {
        gload16(Abase + k0, As + (wid * 2) * 512);
        gload16(Abase + k0 + 16 * K, As + (wid * 2 + 1) * 512);
        gload16(Bbase + k0, Bs + (wid * 2) * 512);
        gload16(Bbase + k0 + 16 * K, Bs + (wid * 2 + 1) * 512);
        __syncthreads();
        bf16x8 af[4], bfr[4];
#pragma unroll
        for (int i = 0; i < 4; ++i) {
            af[i] = ld_b8(As + (wr * 64 + i * 16 + (lane & 15)) * 32 + (lane >> 4) * 8);
            bfr[i] = ld_b8(Bs + (wc * 64 + i * 16 + (lane & 15)) * 32 + (lane >> 4) * 8);
        }
#pragma unroll
        for (int i = 0; i < 4; ++i)
#pragma unroll
            for (int j = 0; j < 4; ++j) acc[i][j] = MFMA16(af[i], bfr[j], acc[i][j]);
        __syncthreads();
    }
    const int crow = m0 + wr * 64 + (lane >> 4) * 4;
    const int ccol = n0 + wc * 64 + (lane & 15);
#pragma unroll
    for (int i = 0; i < 4; ++i)
#pragma unroll
        for (int j = 0; j < 4; ++j)
#pragma unroll
            for (int r = 0; r < 4; ++r) {
                const size_t idx = (size_t)(crow + i * 16 + r) * N + ccol + j * 16;
                if (OUTF)
                    ((float*)Cv)[idx] = acc[i][j][r];
                else
                    ((unsigned short*)Cv)[idx] = f2b(acc[i][j][r]);
            }
}

// ---------------- extract V^T: vt[bh][dh][t] from qkv ----------------
__global__ __launch_bounds__(256) void k_vt(const unsigned short* __restrict__ qkv,
                                            unsigned short* __restrict__ vt) {
    __shared__ unsigned short t_[64][72];
    const int bh = blockIdx.x & 63, tt = blockIdx.x >> 6;
    const int b = bh >> 4, h = bh & 15;
    const int tid = threadIdx.x;
    const int r = tid >> 2, c = (tid & 3) * 16;
    const unsigned short* src =
        qkv + (size_t)(b * T_ + tt * 64 + r) * 3072 + 2048 + h * 64 + c;
    *(u16x8*)&t_[r][c] = *(const u16x8*)src;
    *(u16x8*)&t_[r][c + 8] = *(const u16x8*)(src + 8);
    __syncthreads();
    unsigned short* dst = vt + (size_t)(bh * 64 + r) * T_ + tt * 64 + c;
#pragma unroll
    for (int j = 0; j < 16; ++j) dst[j] = t_[c + j][r];
}

// ---------------- causal flash attention ----------------
// 4 waves, 64 q-rows per q-tile; each block handles TWO q-tiles (qt = 31-p,
// then p) so every block does exactly 33 KV-tiles -> zero drain tail, and
// grid = 1024 = exactly 4 blocks/CU. LDS = 40960 B -> 4 blocks/CU resident.
// Swapped QK^T (S^T = mfma(K,Q)), in-lane row softmax, defer-max, K/V double
// buffer (1 barrier/tile), XOR-swizzled K/V/P (all granule involutions).
__global__ __launch_bounds__(256) void k_attn(const unsigned short* __restrict__ qkv,
                                              const unsigned short* __restrict__ vt,
                                              unsigned short* __restrict__ ao) {
    __shared__ unsigned short Ks[2 * 4096];
    __shared__ unsigned short Vs[2 * 4096];
    __shared__ unsigned short Ps[4][1024];  // per-wave 16x64, XOR-swizzled
    const int bh = blockIdx.x & 63;
    const int p = blockIdx.x >> 6;  // 0..15
    const int b = bh >> 4, h = bh & 15;
    const int tid = threadIdx.x, lane = tid & 63, w = tid >> 6;
    const int l4 = lane >> 4, l15 = lane & 15;
    const int psw = (l15 & 7) << 3;  // P swizzle (shorts)

    const int sr0 = w * 16 + (lane >> 3);
    const int scol = 8 * ((lane & 7) ^ (lane >> 3));  // inverse-swizzled source col
    const unsigned short* Kg = qkv + (size_t)(b * T_) * 3072 + 1024 + h * 64;
    const unsigned short* Vg = vt + (size_t)(bh * 64) * T_;

    for (int half = 0; half < 2; ++half) {
        const int qt = half ? p : 31 - p;  // heavy tile first

        // Q fragment rows q = w*16 + l15, pre-scaled by (1/sqrt(64))*log2(e)
        const unsigned short* qb =
            qkv + (size_t)(b * T_ + qt * 64 + w * 16 + l15) * 3072 + h * 64;
        bf16x8 qf0, qf1;
        {
            const bf16x8 r0 = ld_b8(qb + l4 * 8);
            const bf16x8 r1 = ld_b8(qb + 32 + l4 * 8);
#pragma unroll
            for (int j = 0; j < 8; ++j) {
                qf0[j] = (__bf16)((float)r0[j] * 0.18033688f);
                qf1[j] = (__bf16)((float)r1[j] * 0.18033688f);
            }
        }

        float m_s = -1e30f, l_s = 0.f;  // stats for q = l15 (replicated over l4)
        f32x4 o[4] = {};                // o[ni][r]: row q=l4*4+r, col dh=ni*16+l15

        auto STAGE = [&](int kt, int bi) {
            unsigned short* Kb = Ks + bi * 4096;
            unsigned short* Vb = Vs + bi * 4096;
            gload16(Kg + (size_t)(kt * 64 + sr0) * 3072 + scol, Kb + (w * 2) * 512);
            gload16(Kg + (size_t)(kt * 64 + sr0 + 8) * 3072 + scol, Kb + (w * 2 + 1) * 512);
            gload16(Vg + (size_t)sr0 * T_ + kt * 64 + scol, Vb + (w * 2) * 512);
            gload16(Vg + (size_t)(sr0 + 8) * T_ + kt * 64 + scol, Vb + (w * 2 + 1) * 512);
        };

        auto COMPUTE = [&](int bi, bool masked) {
            const unsigned short* Kb = Ks + bi * 4096;
            const unsigned short* Vb = Vs + bi * 4096;
            float tv[4][4];
            __builtin_amdgcn_s_setprio(1);
#pragma unroll
            for (int i = 0; i < 4; ++i) {
                const int key = i * 16 + l15;
                const int sw = (key & 7) << 4;
                const bf16x8 kf0 = ld_b8(Kb + (key * 128 + ((l4 * 16) ^ sw)) / 2);
                const bf16x8 kf1 = ld_b8(Kb + (key * 128 + ((l4 * 16 + 64) ^ sw)) / 2);
                f32x4 sacc = {};
                sacc = MFMA16(kf0, qf0, sacc);
                sacc = MFMA16(kf1, qf1, sacc);
#pragma unroll
                for (int r = 0; r < 4; ++r) tv[i][r] = sacc[r];
            }
            __builtin_amdgcn_s_setprio(0);
            if (masked) {
#pragma unroll
                for (int i = 0; i < 4; ++i)
#pragma unroll
                    for (int r = 0; r < 4; ++r)
                        if (i * 16 + l4 * 4 + r > w * 16 + l15) tv[i][r] = -1e30f;
            }
            // row max for q=l15: in-lane tree + 2 cross-lane
            float mi[4];
#pragma unroll
            for (int i = 0; i < 4; ++i)
                mi[i] = fmaxf(fmaxf(tv[i][0], tv[i][1]), fmaxf(tv[i][2], tv[i][3]));
            float mx = fmaxf(fmaxf(mi[0], mi[1]), fmaxf(mi[2], mi[3]));
            mx = fmaxf(mx, __shfl_xor(mx, 16));
            mx = fmaxf(mx, __shfl_xor(mx, 32));
            if (__any(mx > m_s + 8.0f)) {  // defer-max
                const float mnew = fmaxf(m_s, mx);
                const float fac = __builtin_amdgcn_exp2f(m_s - mnew);
                m_s = mnew;
                l_s *= fac;
#pragma unroll
                for (int r = 0; r < 4; ++r) {
                    const float fr = __shfl(fac, (l4 << 4) | (l4 * 4 + r));
#pragma unroll
                    for (int ni = 0; ni < 4; ++ni) o[ni][r] *= fr;
                }
            }
            float rs = 0.f;
            unsigned pw[8];
#pragma unroll
            for (int i = 0; i < 4; ++i) {
                float pv[4];
#pragma unroll
                for (int r = 0; r < 4; ++r) {
                    pv[r] = __builtin_amdgcn_exp2f(tv[i][r] - m_s);
                    rs += pv[r];
                }
                pw[i * 2 + 0] = cvt_pk(pv[0], pv[1]);
                pw[i * 2 + 1] = cvt_pk(pv[2], pv[3]);
            }
            rs += __shfl_xor(rs, 16);
            rs += __shfl_xor(rs, 32);
            l_s += rs;
#pragma unroll
            for (int i = 0; i < 4; ++i) {
                const int ps = l15 * 64 + ((i * 16 + l4 * 4) ^ psw);
                *(unsigned*)&Ps[w][ps] = pw[i * 2];
                *(unsigned*)&Ps[w][ps + 2] = pw[i * 2 + 1];
            }
            __builtin_amdgcn_s_setprio(1);
#pragma unroll
            for (int st = 0; st < 2; ++st) {
                const bf16x8 pf = ld_b8(&Ps[w][l15 * 64 + ((st * 32 + l4 * 8) ^ psw)]);
#pragma unroll
                for (int ni = 0; ni < 4; ++ni) {
                    const int dh = ni * 16 + l15;
                    const int sw = (dh & 7) << 4;
                    const bf16x8 vf = ld_b8(Vb + (dh * 128 + ((st * 64 + l4 * 16) ^ sw)) / 2);
                    o[ni] = MFMA16(pf, vf, o[ni]);
                }
            }
            __builtin_amdgcn_s_setprio(0);
        };

        __syncthreads();  // protect LDS reuse across the two halves
        STAGE(0, 0);
        __syncthreads();
        for (int kt = 0; kt < qt; ++kt) {
            STAGE(kt + 1, (kt + 1) & 1);
            COMPUTE(kt & 1, false);
            __syncthreads();
        }
        COMPUTE(qt & 1, true);

        // epilogue: fetch per-row l via shfl, normalize, store bf16 [b,t,h,dh]
        unsigned short* aop = ao + (size_t)(b * T_ + qt * 64 + w * 16) * 1024 + h * 64;
#pragma unroll
        for (int r = 0; r < 4; ++r) {
            const float lr = __shfl(l_s, (l4 << 4) | (l4 * 4 + r));
            const float inv = 1.0f / lr;
#pragma unroll
            for (int ni = 0; ni < 4; ++ni)
                aop[(size_t)(l4 * 4 + r) * 1024 + ni * 16 + l15] = f2b(o[ni][r] * inv);
        }
    }
}

extern "C" void kernel_launch(void* const* d_in, const int* in_sizes, int n_in,
                              void* d_out, int out_size, void* d_ws, size_t ws_size,
                              hipStream_t stream) {
    (void)in_sizes; (void)n_in; (void)out_size; (void)ws_size;
    const float* x = (const float*)d_in[0];
    const float* Wqkv = (const float*)d_in[1];
    const float* Wout = (const float*)d_in[2];
    char* ws = (char*)d_ws;
    unsigned short* xb = (unsigned short*)(ws + 0);             // 16 MB
    unsigned short* wqkvT = (unsigned short*)(ws + 16777216);   // 6 MB  (3072 x 1024)
    unsigned short* woutT = (unsigned short*)(ws + 23068672);   // 2 MB  (1024 x 1024)
    unsigned short* qkvb = (unsigned short*)(ws + 25165824);    // 48 MB (8192 x 3072)
    unsigned short* vt = (unsigned short*)(ws + 75497472);      // 16 MB (64 heads x 64 x 2048)
    unsigned short* ao = (unsigned short*)(ws + 92274688);      // 16 MB (8192 x 1024)

    k_cvt<<<2048, 256, 0, stream>>>(x, xb, 4 * T_ * 1024);
    k_cvt_T<1024, 3072><<<16 * 48, 256, 0, stream>>>(Wqkv, wqkvT);
    k_cvt_T<1024, 1024><<<16 * 16, 256, 0, stream>>>(Wout, woutT);
    k_gemm<1024, 0><<<dim3(24, 64), 256, 0, stream>>>(xb, wqkvT, (void*)qkvb, 3072);
    k_vt<<<2048, 256, 0, stream>>>(qkvb, vt);
    k_attn<<<1024, 256, 0, stream>>>(qkvb, vt, ao);
    k_gemm<1024, 1><<<dim3(8, 64), 256, 0, stream>>>(ao, woutT, d_out, 1024);
}

// Round 4
// 184.324 us; speedup vs baseline: 1.2405x; 1.0182x over previous
//
#include <hip/hip_runtime.h>
#include <stdint.h>

#define T_ 2048
#define BB_ 4

typedef __bf16 bf16x8 __attribute__((ext_vector_type(8)));
typedef float f32x4 __attribute__((ext_vector_type(4)));
typedef unsigned short u16x8 __attribute__((ext_vector_type(8)));
typedef unsigned int u32x2 __attribute__((ext_vector_type(2)));
typedef unsigned int u32x4 __attribute__((ext_vector_type(4)));

__device__ __forceinline__ unsigned short f2b(float f) {
    unsigned int u = __builtin_bit_cast(unsigned int, f);
    return (unsigned short)((u + 0x7fffu + ((u >> 16) & 1u)) >> 16);
}

__device__ __forceinline__ unsigned cvt_pk(float lo, float hi) {
    unsigned r;
    asm("v_cvt_pk_bf16_f32 %0, %1, %2" : "=v"(r) : "v"(lo), "v"(hi));
    return r;
}

__device__ __forceinline__ void gload16(const void* g, const void* lds) {
    __builtin_amdgcn_global_load_lds(
        (__attribute__((address_space(1))) void*)(uintptr_t)g,
        (__attribute__((address_space(3))) void*)(uintptr_t)(unsigned int)(uintptr_t)lds,
        16, 0, 0);
}

__device__ __forceinline__ bf16x8 ld_b8(const unsigned short* p) {
    return *(const bf16x8*)p;
}

#define MFMA16(a, b, c) __builtin_amdgcn_mfma_f32_16x16x32_bf16((a), (b), (c), 0, 0, 0)

// ---------------- fp32 -> bf16 elementwise ----------------
__global__ __launch_bounds__(256) void k_cvt(const float* __restrict__ in,
                                             unsigned short* __restrict__ out, int n) {
    int i = (blockIdx.x * 256 + threadIdx.x) * 4;
    const int stride = gridDim.x * 256 * 4;
    for (; i < n; i += stride) {
        const float4 v = *(const float4*)(in + i);
        ushort4 o = make_ushort4(f2b(v.x), f2b(v.y), f2b(v.z), f2b(v.w));
        *(ushort4*)(out + i) = o;
    }
}

// ---------------- fp32 (K x N) -> bf16 transposed (N x K) ----------------
template <int K, int N>
__global__ __launch_bounds__(256) void k_cvt_T(const float* __restrict__ W,
                                               unsigned short* __restrict__ WT) {
    __shared__ unsigned short t_[64][72];
    const int nt = blockIdx.x % (N / 64), kt = blockIdx.x / (N / 64);
    const int tid = threadIdx.x;
    const int r = tid >> 2, c = (tid & 3) * 16;
    const float* src = W + (size_t)(kt * 64 + r) * N + nt * 64 + c;
#pragma unroll
    for (int j = 0; j < 16; j += 4) {
        float4 v = *(const float4*)(src + j);
        t_[r][c + j + 0] = f2b(v.x);
        t_[r][c + j + 1] = f2b(v.y);
        t_[r][c + j + 2] = f2b(v.z);
        t_[r][c + j + 3] = f2b(v.w);
    }
    __syncthreads();
    unsigned short* dst = WT + (size_t)(nt * 64 + r) * K + kt * 64 + c;
#pragma unroll
    for (int j = 0; j < 16; ++j) dst[j] = t_[c + j][r];
}

// ---------------- bf16 GEMM: C[M][N] = A[M][K] * Bt[N][K]^T ----------------
template <int K, int OUTF>
__global__ __launch_bounds__(256) void k_gemm(const unsigned short* __restrict__ A,
                                              const unsigned short* __restrict__ Bt,
                                              void* __restrict__ Cv, int N) {
    __shared__ unsigned short As[128 * 32];
    __shared__ unsigned short Bs[128 * 32];
    const int tid = threadIdx.x;
    const int lane = tid & 63;
    const int wid = tid >> 6;
    const int wr = wid >> 1, wc = wid & 1;
    const int m0 = blockIdx.y * 128, n0 = blockIdx.x * 128;
    const int arow = lane >> 2;
    const int acol = (lane & 3) * 8;
    f32x4 acc[4][4] = {};

    const unsigned short* Abase = A + (size_t)(m0 + wid * 32 + arow) * K + acol;
    const unsigned short* Bbase = Bt + (size_t)(n0 + wid * 32 + arow) * K + acol;

    for (int k0 = 0; k0 < K; k0 += 32) {
        gload16(Abase + k0, As + (wid * 2) * 512);
        gload16(Abase + k0 + 16 * K, As + (wid * 2 + 1) * 512);
        gload16(Bbase + k0, Bs + (wid * 2) * 512);
        gload16(Bbase + k0 + 16 * K, Bs + (wid * 2 + 1) * 512);
        __syncthreads();
        bf16x8 af[4], bfr[4];
#pragma unroll
        for (int i = 0; i < 4; ++i) {
            af[i] = ld_b8(As + (wr * 64 + i * 16 + (lane & 15)) * 32 + (lane >> 4) * 8);
            bfr[i] = ld_b8(Bs + (wc * 64 + i * 16 + (lane & 15)) * 32 + (lane >> 4) * 8);
        }
#pragma unroll
        for (int i = 0; i < 4; ++i)
#pragma unroll
            for (int j = 0; j < 4; ++j) acc[i][j] = MFMA16(af[i], bfr[j], acc[i][j]);
        __syncthreads();
    }
    const int crow = m0 + wr * 64 + (lane >> 4) * 4;
    const int ccol = n0 + wc * 64 + (lane & 15);
#pragma unroll
    for (int i = 0; i < 4; ++i)
#pragma unroll
        for (int j = 0; j < 4; ++j)
#pragma unroll
            for (int r = 0; r < 4; ++r) {
                const size_t idx = (size_t)(crow + i * 16 + r) * N + ccol + j * 16;
                if (OUTF)
                    ((float*)Cv)[idx] = acc[i][j][r];
                else
                    ((unsigned short*)Cv)[idx] = f2b(acc[i][j][r]);
            }
}

// ---------------- extract V into vt2[bh][t/4][dh][4] from qkv ----------------
// Layout chosen so k_attn can stage V tiles with linear global_load_lds into
// a [key-quad][dh][4] LDS blocking that is bank-conflict-free for sigma-PV.
__global__ __launch_bounds__(256) void k_vt(const unsigned short* __restrict__ qkv,
                                            unsigned short* __restrict__ vt2) {
    __shared__ unsigned short t_[64][72];
    const int bh = blockIdx.x & 63, tt = blockIdx.x >> 6;
    const int b = bh >> 4, h = bh & 15;
    const int tid = threadIdx.x;
    const int r = tid >> 2, c = (tid & 3) * 16;
    const unsigned short* src =
        qkv + (size_t)(b * T_ + tt * 64 + r) * 3072 + 2048 + h * 64 + c;
    *(u16x8*)&t_[r][c] = *(const u16x8*)src;
    *(u16x8*)&t_[r][c + 8] = *(const u16x8*)(src + 8);
    __syncthreads();
    // t_[t_local][dh] -> vt2[bh][tt*16 + tq][dh][j]
    const int dh = tid & 63, tg = tid >> 6;
    unsigned short* dst = vt2 + (size_t)bh * 131072 + (size_t)(tt * 16) * 256 + dh * 4;
#pragma unroll
    for (int u = 0; u < 4; ++u) {
        const int tq = tg * 4 + u;
        ushort4 o;
        o.x = t_[tq * 4 + 0][dh];
        o.y = t_[tq * 4 + 1][dh];
        o.z = t_[tq * 4 + 2][dh];
        o.w = t_[tq * 4 + 3][dh];
        *(ushort4*)(dst + tq * 256) = o;
    }
}

// ---------------- causal flash attention ----------------
// 4 waves, 64 q-rows per q-tile; each block handles TWO q-tiles (qt = 31-p,
// then p): every block does exactly 33 KV-tiles, grid = 1024.
// LDS = 32 KiB -> 4 blocks/CU resident (50% occupancy cap).
// Swapped QK^T (S^T = mfma(K,Q)); P never touches LDS: the PV k-dim is
// permuted by sigma so each lane's A-fragment is exactly its own cvt_pk
// words; V is blocked [key-quad][dh][4] in LDS (conflict-free b64 reads).
__global__ __launch_bounds__(256) void k_attn(const unsigned short* __restrict__ qkv,
                                              const unsigned short* __restrict__ vt2,
                                              unsigned short* __restrict__ ao) {
    __shared__ unsigned short Ks[2 * 4096];
    __shared__ unsigned short Vs[2 * 4096];
    const int bh = blockIdx.x & 63;
    const int p = blockIdx.x >> 6;  // 0..15
    const int b = bh >> 4, h = bh & 15;
    const int tid = threadIdx.x, lane = tid & 63, w = tid >> 6;
    const int l4 = lane >> 4, l15 = lane & 15;

    // K staging geometry (XOR-swizzled rows, 16B granule)
    const int sr0 = w * 16 + (lane >> 3);
    const int scol = 8 * ((lane & 7) ^ (lane >> 3));
    const unsigned short* Kg = qkv + (size_t)(b * T_) * 3072 + 1024 + h * 64;

    // V staging geometry: LDS slot s holds global key-quad kq = 4*(s&3)+(s>>2)
    // (so that LDS slot order is l4*4 + i, matching the sigma-PV reads).
    const unsigned short* Vg = vt2 + (size_t)bh * 131072;
    const int s0v = (w * 2 + 0) * 2 + (lane >> 5);
    const int s1v = (w * 2 + 1) * 2 + (lane >> 5);
    const unsigned short* vsrc0 =
        Vg + (4 * (s0v & 3) + (s0v >> 2)) * 256 + (lane & 31) * 8;
    const unsigned short* vsrc1 =
        Vg + (4 * (s1v & 3) + (s1v >> 2)) * 256 + (lane & 31) * 8;

    for (int half = 0; half < 2; ++half) {
        const int qt = half ? p : 31 - p;  // heavy tile first

        // Q fragment rows q = w*16 + l15, pre-scaled by (1/sqrt(64))*log2(e)
        const unsigned short* qb =
            qkv + (size_t)(b * T_ + qt * 64 + w * 16 + l15) * 3072 + h * 64;
        bf16x8 qf0, qf1;
        {
            const bf16x8 r0 = ld_b8(qb + l4 * 8);
            const bf16x8 r1 = ld_b8(qb + 32 + l4 * 8);
#pragma unroll
            for (int j = 0; j < 8; ++j) {
                qf0[j] = (__bf16)((float)r0[j] * 0.18033688f);
                qf1[j] = (__bf16)((float)r1[j] * 0.18033688f);
            }
        }

        float m_s = -1e30f, l_s = 0.f;  // stats for q = l15 (replicated over l4)
        f32x4 o[4] = {};                // o[ni][r]: row q=l4*4+r, col dh=ni*16+l15

        auto STAGE = [&](int kt, int bi) {
            unsigned short* Kb = Ks + bi * 4096;
            unsigned short* Vb = Vs + bi * 4096;
            gload16(Kg + (size_t)(kt * 64 + sr0) * 3072 + scol, Kb + (w * 2) * 512);
            gload16(Kg + (size_t)(kt * 64 + sr0 + 8) * 3072 + scol, Kb + (w * 2 + 1) * 512);
            gload16(vsrc0 + kt * 4096, Vb + (w * 2) * 512);
            gload16(vsrc1 + kt * 4096, Vb + (w * 2 + 1) * 512);
        };

        auto COMPUTE = [&](int bi, bool masked) {
            const unsigned short* Kb = Ks + bi * 4096;
            const unsigned short* Vb = Vs + bi * 4096;
            float tv[4][4];
            __builtin_amdgcn_s_setprio(1);
#pragma unroll
            for (int i = 0; i < 4; ++i) {
                const int key = i * 16 + l15;
                const int sw = (key & 7) << 4;
                const bf16x8 kf0 = ld_b8(Kb + (key * 128 + ((l4 * 16) ^ sw)) / 2);
                const bf16x8 kf1 = ld_b8(Kb + (key * 128 + ((l4 * 16 + 64) ^ sw)) / 2);
                f32x4 sacc = {};
                sacc = MFMA16(kf0, qf0, sacc);
                sacc = MFMA16(kf1, qf1, sacc);
#pragma unroll
                for (int r = 0; r < 4; ++r) tv[i][r] = sacc[r];
            }
            __builtin_amdgcn_s_setprio(0);
            if (masked) {
#pragma unroll
                for (int i = 0; i < 4; ++i)
#pragma unroll
                    for (int r = 0; r < 4; ++r)
                        if (i * 16 + l4 * 4 + r > w * 16 + l15) tv[i][r] = -1e30f;
            }
            // row max for q=l15: in-lane tree + 2 cross-lane
            float mi[4];
#pragma unroll
            for (int i = 0; i < 4; ++i)
                mi[i] = fmaxf(fmaxf(tv[i][0], tv[i][1]), fmaxf(tv[i][2], tv[i][3]));
            float mx = fmaxf(fmaxf(mi[0], mi[1]), fmaxf(mi[2], mi[3]));
            mx = fmaxf(mx, __shfl_xor(mx, 16));
            mx = fmaxf(mx, __shfl_xor(mx, 32));
            if (__any(mx > m_s + 8.0f)) {  // defer-max
                const float mnew = fmaxf(m_s, mx);
                const float fac = __builtin_amdgcn_exp2f(m_s - mnew);
                m_s = mnew;
                l_s *= fac;
#pragma unroll
                for (int r = 0; r < 4; ++r) {
                    const float fr = __shfl(fac, (l4 << 4) | (l4 * 4 + r));
#pragma unroll
                    for (int ni = 0; ni < 4; ++ni) o[ni][r] *= fr;
                }
            }
            float rs = 0.f;
            unsigned pw[8];  // pw[i*2+c]: P(keys i*16 + l4*4 + 2c, +2c+1), q=l15
#pragma unroll
            for (int i = 0; i < 4; ++i) {
                float pv[4];
#pragma unroll
                for (int r = 0; r < 4; ++r) {
                    pv[r] = __builtin_amdgcn_exp2f(tv[i][r] - m_s);
                    rs += pv[r];
                }
                pw[i * 2 + 0] = cvt_pk(pv[0], pv[1]);
                pw[i * 2 + 1] = cvt_pk(pv[2], pv[3]);
            }
            rs += __shfl_xor(rs, 16);
            rs += __shfl_xor(rs, 32);
            l_s += rs;
            // sigma-PV: A-fragment = own pw words; B from Vs[slot=l4*4+st*2+b][dh][4]
            __builtin_amdgcn_s_setprio(1);
#pragma unroll
            for (int st = 0; st < 2; ++st) {
                const u32x4 pk = {pw[st * 4 + 0], pw[st * 4 + 1], pw[st * 4 + 2],
                                  pw[st * 4 + 3]};
                const bf16x8 pf = __builtin_bit_cast(bf16x8, pk);
#pragma unroll
                for (int ni = 0; ni < 4; ++ni) {
                    const unsigned short* vb =
                        Vb + (l4 * 4 + st * 2) * 256 + (ni * 16 + l15) * 4;
                    const u32x2 va = *(const u32x2*)vb;
                    const u32x2 vc = *(const u32x2*)(vb + 256);
                    const u32x4 vv = {va.x, va.y, vc.x, vc.y};
                    const bf16x8 vf = __builtin_bit_cast(bf16x8, vv);
                    o[ni] = MFMA16(pf, vf, o[ni]);
                }
            }
            __builtin_amdgcn_s_setprio(0);
        };

        __syncthreads();  // protect LDS reuse across the two halves
        STAGE(0, 0);
        __syncthreads();
        for (int kt = 0; kt < qt; ++kt) {
            STAGE(kt + 1, (kt + 1) & 1);
            COMPUTE(kt & 1, false);
            __syncthreads();
        }
        COMPUTE(qt & 1, true);

        // epilogue: fetch per-row l via shfl, normalize, store bf16 [b,t,h,dh]
        unsigned short* aop = ao + (size_t)(b * T_ + qt * 64 + w * 16) * 1024 + h * 64;
#pragma unroll
        for (int r = 0; r < 4; ++r) {
            const float lr = __shfl(l_s, (l4 << 4) | (l4 * 4 + r));
            const float inv = 1.0f / lr;
#pragma unroll
            for (int ni = 0; ni < 4; ++ni)
                aop[(size_t)(l4 * 4 + r) * 1024 + ni * 16 + l15] = f2b(o[ni][r] * inv);
        }
    }
}

extern "C" void kernel_launch(void* const* d_in, const int* in_sizes, int n_in,
                              void* d_out, int out_size, void* d_ws, size_t ws_size,
                              hipStream_t stream) {
    (void)in_sizes; (void)n_in; (void)out_size; (void)ws_size;
    const float* x = (const float*)d_in[0];
    const float* Wqkv = (const float*)d_in[1];
    const float* Wout = (const float*)d_in[2];
    char* ws = (char*)d_ws;
    unsigned short* xb = (unsigned short*)(ws + 0);             // 16 MB
    unsigned short* wqkvT = (unsigned short*)(ws + 16777216);   // 6 MB  (3072 x 1024)
    unsigned short* woutT = (unsigned short*)(ws + 23068672);   // 2 MB  (1024 x 1024)
    unsigned short* qkvb = (unsigned short*)(ws + 25165824);    // 48 MB (8192 x 3072)
    unsigned short* vt2 = (unsigned short*)(ws + 75497472);     // 16 MB (64 x 512 x 64 x 4)
    unsigned short* ao = (unsigned short*)(ws + 92274688);      // 16 MB (8192 x 1024)

    k_cvt<<<2048, 256, 0, stream>>>(x, xb, 4 * T_ * 1024);
    k_cvt_T<1024, 3072><<<16 * 48, 256, 0, stream>>>(Wqkv, wqkvT);
    k_cvt_T<1024, 1024><<<16 * 16, 256, 0, stream>>>(Wout, woutT);
    k_gemm<1024, 0><<<dim3(24, 64), 256, 0, stream>>>(xb, wqkvT, (void*)qkvb, 3072);
    k_vt<<<2048, 256, 0, stream>>>(qkvb, vt2);
    k_attn<<<1024, 256, 0, stream>>>(qkvb, vt2, ao);
    k_gemm<1024, 1><<<dim3(8, 64), 256, 0, stream>>>(ao, woutT, d_out, 1024);
}